// Round 20
// baseline (4156.152 us; speedup 1.0000x reference)
//
#include <hip/hip_runtime.h>
#include <stdint.h>

// ============================ problem constants ============================
#define C_DIM   768
#define N_TOK   193
#define B_TOT   64                    // 2 towers x 32 batch
#define ROWS    (B_TOT * N_TOK)       // 12352
#define QKV_DIM 2304
#define N_HEAD  12
#define N_EXP   8
#define MAXPER  ROWS
#define RTOK    64                    // tokens per router block

enum { MODE_PLAIN = 1, MODE_RESID = 2, MODE_EXPERT = 3 };

typedef __attribute__((ext_vector_type(8))) short bf16x8;
typedef __attribute__((ext_vector_type(4))) float f32x4;

// Packed bf16x2-split format: per 16-element K-chunk, [hi x16][lo x16] shorts.
// Element (r,k) of an [R][K] matrix: hi at r*2K + (k>>4)*32 + (k&15), lo at +16.

// ============================ threefry-2x32 (bit-exact vs JAX) ============================
__device__ __forceinline__ uint32_t rotl32(uint32_t x, int n){ return (x << n) | (x >> (32 - n)); }

__device__ __forceinline__ void tf2x32(uint32_t k0, uint32_t k1, uint32_t x0, uint32_t x1,
                                       uint32_t &r0, uint32_t &r1){
  uint32_t k2 = k0 ^ k1 ^ 0x1BD11BDAu;
#define TF4(a,b,c,d) x0+=x1; x1=rotl32(x1,a); x1^=x0; x0+=x1; x1=rotl32(x1,b); x1^=x0; \
                     x0+=x1; x1=rotl32(x1,c); x1^=x0; x0+=x1; x1=rotl32(x1,d); x1^=x0;
  x0 += k0; x1 += k1;
  TF4(13,15,26, 6)  x0 += k1; x1 += k2 + 1u;
  TF4(17,29,16,24)  x0 += k2; x1 += k0 + 2u;
  TF4(13,15,26, 6)  x0 += k0; x1 += k1 + 3u;
  TF4(17,29,16,24)  x0 += k1; x1 += k2 + 4u;
  TF4(13,15,26, 6)  x0 += k2; x1 += k0 + 5u;
#undef TF4
  r0 = x0; r1 = x1;
}

__device__ __forceinline__ float jax_erfinv(float x){
  float w = -log1pf(-x * x);
  float p;
  if (w < 5.0f){
    w -= 2.5f;
    p =              2.81022636e-08f;
    p = fmaf(p, w,   3.43273939e-07f);
    p = fmaf(p, w,  -3.5233877e-06f);
    p = fmaf(p, w,  -4.39150654e-06f);
    p = fmaf(p, w,   0.00021858087f);
    p = fmaf(p, w,  -0.00125372503f);
    p = fmaf(p, w,  -0.00417768164f);
    p = fmaf(p, w,   0.246640727f);
    p = fmaf(p, w,   1.50140941f);
  } else {
    w = sqrtf(w) - 3.0f;
    p =             -0.000200214257f;
    p = fmaf(p, w,   0.000100950558f);
    p = fmaf(p, w,   0.00134934322f);
    p = fmaf(p, w,  -0.00367342844f);
    p = fmaf(p, w,   0.00573950773f);
    p = fmaf(p, w,  -0.0076224613f);
    p = fmaf(p, w,   0.00943887047f);
    p = fmaf(p, w,   1.00167406f);
    p = fmaf(p, w,   2.83297682f);
  }
  return p * x;
}

// PARTITIONABLE threefry random_bits (JAX >= 0.4.36 default) [verified round 5]
__device__ __forceinline__ float jax_noise(uint32_t c0, uint32_t c1, uint32_t j){
  uint32_t o0, o1;
  tf2x32(c0, c1, 0u, j, o0, o1);
  uint32_t bits = o0 ^ o1;
  float f = __uint_as_float(0x3f800000u | (bits >> 9)) - 1.0f;   // [0,1)
  const float lo = -0.99999994f;                                  // nextafter(-1,0)
  float u = fmaxf(lo, f * 2.0f + lo);
  return 1.41421356237f * jax_erfinv(u) * 0.125f;                 // sqrt(2)*erfinv(u)/E
}

// ============================ bf16 split helpers ============================
__device__ __forceinline__ unsigned short f2bf(float x){
  union { float f; uint32_t u; } v; v.f = x;
  uint32_t u = v.u;
  uint32_t r = (u + 0x7FFFu + ((u >> 16) & 1u)) >> 16;   // RNE
  return (unsigned short)r;
}
__device__ __forceinline__ float bf2f(unsigned short h){
  union { uint32_t u; float f; } v; v.u = ((uint32_t)h) << 16;
  return v.f;
}
// truncation split: hi = trunc_bf16(x) (x - hi exact); lo = RNE_bf16(x - hi). [validated R15/R16]
__device__ __forceinline__ void fsplit_t(float x, short &hi, short &lo){
  union { float f; uint32_t u; } v; v.f = x;
  uint32_t hb = v.u & 0xFFFF0000u;
  hi = (short)(hb >> 16);
  union { uint32_t u; float f; } hv; hv.u = hb;
  lo = (short)f2bf(x - hv.f);
}

// ============================ small kernels ============================
__global__ __launch_bounds__(64) void k_sentinel(float* __restrict__ out, float v){
  if (threadIdx.x == 0) out[0] = v;
}

// fp32 matrix -> packed split (chunk layout). nchunk = elements/16.
__global__ __launch_bounds__(256) void k_wsplit(const float* __restrict__ w, short* __restrict__ o, int nchunk){
  for (int g = blockIdx.x * 256 + threadIdx.x; g < nchunk; g += gridDim.x * 256){
    const float* src = w + (size_t)g * 16;
    float v[16];
    *(float4*)&v[0]  = *(const float4*)(src);
    *(float4*)&v[4]  = *(const float4*)(src + 4);
    *(float4*)&v[8]  = *(const float4*)(src + 8);
    *(float4*)&v[12] = *(const float4*)(src + 12);
    short hi[16], lo[16];
    #pragma unroll
    for (int j = 0; j < 16; ++j) fsplit_t(v[j], hi[j], lo[j]);
    short* dst = o + (size_t)g * 32;
    *(bf16x8*)(dst)      = *(bf16x8*)&hi[0];
    *(bf16x8*)(dst + 8)  = *(bf16x8*)&hi[8];
    *(bf16x8*)(dst + 16) = *(bf16x8*)&lo[0];
    *(bf16x8*)(dst + 24) = *(bf16x8*)&lo[8];
  }
}

__global__ __launch_bounds__(256) void k_cls(float* __restrict__ h, const float* __restrict__ cls,
                                             const float* __restrict__ pos){
  const int bt = blockIdx.x;
  #pragma unroll
  for (int u = 0; u < 3; ++u){
    int c = threadIdx.x + u * 256;
    h[(size_t)bt * N_TOK * C_DIM + c] = cls[c] + pos[c];
  }
}

__device__ __forceinline__ float blk_sum(float v, float* sb){
  #pragma unroll
  for (int off = 32; off > 0; off >>= 1) v += __shfl_down(v, off, 64);
  const int lane = threadIdx.x & 63, w = threadIdx.x >> 6;
  if (lane == 0) sb[w] = v;
  __syncthreads();
  if (threadIdx.x == 0) sb[4] = sb[0] + sb[1] + sb[2] + sb[3];
  __syncthreads();
  float r = sb[4];
  __syncthreads();
  return r;
}

__device__ __forceinline__ void pk_write(short* __restrict__ ypk, size_t rowbase2, int col, float o){
  short h_, l_;
  fsplit_t(o, h_, l_);
  size_t ix = rowbase2 + (size_t)(col >> 4) * 32 + (col & 15);
  ypk[ix] = h_;
  ypk[ix + 16] = l_;
}

// layernorm; optional fp32 out (router needs it), always packed out; block 0 zeroes ecnt if given
__global__ __launch_bounds__(256) void k_layernorm(const float* __restrict__ x, float* __restrict__ yf,
                                                   short* __restrict__ ypk,
                                                   const float* __restrict__ w, const float* __restrict__ b,
                                                   int* __restrict__ ecnt){
  __shared__ float sb[8];
  if (ecnt && blockIdx.x == 0 && threadIdx.x < N_EXP) ecnt[threadIdx.x] = 0;
  const float* xr = x + (size_t)blockIdx.x * C_DIM;
  float v0 = xr[threadIdx.x], v1 = xr[threadIdx.x + 256], v2 = xr[threadIdx.x + 512];
  float mean = blk_sum(v0 + v1 + v2, sb) * (1.0f / 768.0f);
  float d0 = v0 - mean, d1 = v1 - mean, d2 = v2 - mean;
  float var = blk_sum(d0 * d0 + d1 * d1 + d2 * d2, sb) * (1.0f / 768.0f);
  float inv = 1.0f / sqrtf(var + 1e-5f);
  float o0 = d0 * inv * w[threadIdx.x]       + b[threadIdx.x];
  float o1 = d1 * inv * w[threadIdx.x + 256] + b[threadIdx.x + 256];
  float o2 = d2 * inv * w[threadIdx.x + 512] + b[threadIdx.x + 512];
  if (yf){
    float* yr = yf + (size_t)blockIdx.x * C_DIM;
    yr[threadIdx.x] = o0; yr[threadIdx.x + 256] = o1; yr[threadIdx.x + 512] = o2;
  }
  const size_t pb = (size_t)blockIdx.x * C_DIM * 2;
  pk_write(ypk, pb, threadIdx.x, o0);
  pk_write(ypk, pb, threadIdx.x + 256, o1);
  pk_write(ypk, pb, threadIdx.x + 512, o2);
}

// combine (h += w0*e0 + w1*e1) fused with next layer's ln1; emits packed y only
__global__ __launch_bounds__(256) void k_combine_ln(
    float* __restrict__ h, const float* __restrict__ eout, const float* __restrict__ topw,
    short* __restrict__ ypk, const float* __restrict__ w, const float* __restrict__ b)
{
  __shared__ float sb[8];
  const int tok = blockIdx.x;
  const float w0 = topw[tok * 2], w1 = topw[tok * 2 + 1];
  const size_t hb = (size_t)tok * C_DIM;
  const size_t e0 = (size_t)(tok * 2) * C_DIM, e1 = e0 + C_DIM;
  const int t = threadIdx.x;
  float v0 = h[hb + t]       + (w0 * eout[e0 + t]       + w1 * eout[e1 + t]);
  float v1 = h[hb + t + 256] + (w0 * eout[e0 + t + 256] + w1 * eout[e1 + t + 256]);
  float v2 = h[hb + t + 512] + (w0 * eout[e0 + t + 512] + w1 * eout[e1 + t + 512]);
  h[hb + t]       = v0;
  h[hb + t + 256] = v1;
  h[hb + t + 512] = v2;
  float mean = blk_sum(v0 + v1 + v2, sb) * (1.0f / 768.0f);
  float d0 = v0 - mean, d1 = v1 - mean, d2 = v2 - mean;
  float var = blk_sum(d0 * d0 + d1 * d1 + d2 * d2, sb) * (1.0f / 768.0f);
  float inv = 1.0f / sqrtf(var + 1e-5f);
  const size_t pb = (size_t)tok * C_DIM * 2;
  pk_write(ypk, pb, t,       d0 * inv * w[t]       + b[t]);
  pk_write(ypk, pb, t + 256, d1 * inv * w[t + 256] + b[t + 256]);
  pk_write(ypk, pb, t + 512, d2 * inv * w[t + 512] + b[t + 512]);
}

__global__ __launch_bounds__(256) void k_final(const float* __restrict__ h, float* __restrict__ out,
                                               const float* __restrict__ w, const float* __restrict__ b){
  __shared__ float sb[8];
  const int bt = blockIdx.x;
  const float* xr = h + (size_t)bt * N_TOK * C_DIM;
  float v0 = xr[threadIdx.x], v1 = xr[threadIdx.x + 256], v2 = xr[threadIdx.x + 512];
  float mean = blk_sum(v0 + v1 + v2, sb) * (1.0f / 768.0f);
  float d0 = v0 - mean, d1 = v1 - mean, d2 = v2 - mean;
  float var = blk_sum(d0 * d0 + d1 * d1 + d2 * d2, sb) * (1.0f / 768.0f);
  float inv = 1.0f / sqrtf(var + 1e-5f);
  float* orow = out + (size_t)(bt & 31) * 1536 + (size_t)(bt >> 5) * C_DIM;
  orow[threadIdx.x]       = d0 * inv * w[threadIdx.x]       + b[threadIdx.x];
  orow[threadIdx.x + 256] = d1 * inv * w[threadIdx.x + 256] + b[threadIdx.x + 256];
  orow[threadIdx.x + 512] = d2 * inv * w[threadIdx.x + 512] + b[threadIdx.x + 512];
}

// ============================ packed-input MFMA GEMM (no in-kernel split) ============================
template<int MODE>
__global__ __launch_bounds__(256) void k_pgemm(
    const short* __restrict__ Apk, const short* __restrict__ Wpk,
    const float* __restrict__ bias, float* __restrict__ C,
    int M, int Nc, int Kc,
    const int* __restrict__ elist, const int* __restrict__ ecnt)
{
  __shared__ short sAhi[128][40];
  __shared__ short sAlo[128][40];
  __shared__ short sBhi[128][40];
  __shared__ short sBlo[128][40];

  const int tid = threadIdx.x;

  int e = 0;
  int Mloc = M;
  const short* Wp = Wpk;
  const float* bp = bias;
  if constexpr (MODE == MODE_EXPERT){
    e = blockIdx.z;
    Mloc = ecnt[e];
    Wp = Wpk + (size_t)e * C_DIM * C_DIM * 2;
    bp = bias + e * C_DIM;
  }
  const int row0 = blockIdx.x * 128;
  const int col0 = blockIdx.y * 128;
  if (row0 >= Mloc) return;

  const int srow = tid >> 1;
  const int skh  = (tid & 1) * 16;

  const short* arow = Apk;
  bool avalid = false;
  if constexpr (MODE == MODE_PLAIN || MODE == MODE_RESID){
    int r = row0 + srow;
    avalid = r < Mloc;
    arow = Apk + (size_t)(avalid ? r : 0) * 2 * Kc;
  } else {
    int r = row0 + srow;
    avalid = r < Mloc;
    if (avalid) arow = Apk + (size_t)(elist[e * MAXPER + r] >> 1) * 2 * C_DIM;
  }
  const short* brow = Wp + (size_t)(col0 + srow) * 2 * Kc;

  const int wv = tid >> 6;
  const int wr = (wv >> 1) * 64;
  const int wc = (wv & 1) * 64;
  const int lane = tid & 63;
  const int lrow = lane & 15;
  const int lkh  = (lane >> 4) * 8;

  f32x4 acc[4][4] = {};

  bf16x8 a0, a1, a2, a3, b0, b1, b2, b3;
  auto loadA = [&](int k0){
    if (avalid){
      const short* p = arow + (size_t)k0 * 2;
      a0 = *(const bf16x8*)(p);
      a1 = *(const bf16x8*)(p + 8);
      a2 = *(const bf16x8*)(p + 16);
      a3 = *(const bf16x8*)(p + 24);
    } else {
      bf16x8 z = {0,0,0,0,0,0,0,0};
      a0 = z; a1 = z; a2 = z; a3 = z;
    }
  };
  auto loadB = [&](int k0){
    const short* p = brow + (size_t)k0 * 2;
    b0 = *(const bf16x8*)(p);
    b1 = *(const bf16x8*)(p + 8);
    b2 = *(const bf16x8*)(p + 16);
    b3 = *(const bf16x8*)(p + 24);
  };

  loadA(skh);
  loadB(skh);

  const int nkt = Kc / 32;
  for (int kt = 0; kt < nkt; ++kt){
    *(bf16x8*)&sAhi[srow][skh]     = a0;
    *(bf16x8*)&sAhi[srow][skh + 8] = a1;
    *(bf16x8*)&sAlo[srow][skh]     = a2;
    *(bf16x8*)&sAlo[srow][skh + 8] = a3;
    *(bf16x8*)&sBhi[srow][skh]     = b0;
    *(bf16x8*)&sBhi[srow][skh + 8] = b1;
    *(bf16x8*)&sBlo[srow][skh]     = b2;
    *(bf16x8*)&sBlo[srow][skh + 8] = b3;
    __syncthreads();
    if (kt + 1 < nkt){
      loadA((kt + 1) * 32 + skh);
      loadB((kt + 1) * 32 + skh);
    }
    bf16x8 ahi[4], alo[4], bhi[4], blo[4];
    #pragma unroll
    for (int i = 0; i < 4; ++i){
      ahi[i] = *(const bf16x8*)&sAhi[wr + i * 16 + lrow][lkh];
      alo[i] = *(const bf16x8*)&sAlo[wr + i * 16 + lrow][lkh];
    }
    #pragma unroll
    for (int j = 0; j < 4; ++j){
      bhi[j] = *(const bf16x8*)&sBhi[wc + j * 16 + lrow][lkh];
      blo[j] = *(const bf16x8*)&sBlo[wc + j * 16 + lrow][lkh];
    }
    #pragma unroll
    for (int i = 0; i < 4; ++i)
      #pragma unroll
      for (int j = 0; j < 4; ++j){
        acc[i][j] = __builtin_amdgcn_mfma_f32_16x16x32_bf16(ahi[i], bhi[j], acc[i][j], 0, 0, 0);
        acc[i][j] = __builtin_amdgcn_mfma_f32_16x16x32_bf16(ahi[i], blo[j], acc[i][j], 0, 0, 0);
        acc[i][j] = __builtin_amdgcn_mfma_f32_16x16x32_bf16(alo[i], bhi[j], acc[i][j], 0, 0, 0);
      }
    __syncthreads();
  }

  #pragma unroll
  for (int i = 0; i < 4; ++i){
    const int rbase = row0 + wr + i * 16 + (lane >> 4) * 4;
    #pragma unroll
    for (int r = 0; r < 4; ++r){
      const int rg = rbase + r;
      if (rg >= Mloc) continue;
      if constexpr (MODE == MODE_PLAIN){
        size_t orow = (size_t)rg * Nc;
        #pragma unroll
        for (int j = 0; j < 4; ++j){
          int cg = col0 + wc + j * 16 + (lane & 15);
          C[orow + cg] = acc[i][j][r] + bp[cg];
        }
      } else if constexpr (MODE == MODE_RESID){
        size_t orow = (size_t)rg * Nc;
        #pragma unroll
        for (int j = 0; j < 4; ++j){
          int cg = col0 + wc + j * 16 + (lane & 15);
          C[orow + cg] += acc[i][j][r] + bp[cg];
        }
      } else {
        int ts = elist[e * MAXPER + rg];
        size_t orow = (size_t)ts * C_DIM;
        #pragma unroll
        for (int j = 0; j < 4; ++j){
          int cg = col0 + wc + j * 16 + (lane & 15);
          C[orow + cg] = acc[i][j][r] + bp[cg];
        }
      }
    }
  }
}

// ============================ patch-embed GEMM (gather+split A, packed W) ============================
__global__ __launch_bounds__(256) void k_mgemm_patch(
    const short* __restrict__ Wpk, const float* __restrict__ bias, float* __restrict__ C,
    const float* __restrict__ xa, const float* __restrict__ xb, const float* __restrict__ pos)
{
  __shared__ short sAhi[128][40];
  __shared__ short sAlo[128][40];
  __shared__ short sBhi[128][40];
  __shared__ short sBlo[128][40];

  const int tid = threadIdx.x;
  const int Kc = 2304;
  const int row0 = blockIdx.x * 128;
  const int col0 = blockIdx.y * 128;

  const int srow = tid >> 1;
  const int skh  = (tid & 1) * 16;

  const float* psrc;
  {
    int r = row0 + srow;
    int bt = r / 192;
    int n  = r - bt * 192;
    const float* xp = (bt < 32) ? xa : xb;
    psrc = xp + (size_t)(bt & 31) * 3 * 384 * 384 + n * 2;
  }
  const short* brow = Wpk + (size_t)(col0 + srow) * 2 * Kc;

  const int wv = tid >> 6;
  const int wr = (wv >> 1) * 64;
  const int wc = (wv & 1) * 64;
  const int lane = tid & 63;
  const int lrow = lane & 15;
  const int lkh  = (lane >> 4) * 8;

  f32x4 acc[4][4] = {};

  float va[16];
  bf16x8 b0, b1, b2, b3;
  auto loadA = [&](int k0){
    int c   = k0 / 768;
    int rem = k0 - c * 768;
    const float* pc = psrc + ((size_t)c * 384 + (rem >> 1)) * 384;
    #pragma unroll
    for (int m = 0; m < 8; ++m){
      va[m * 2 + 0] = pc[(size_t)m * 384 + 0];
      va[m * 2 + 1] = pc[(size_t)m * 384 + 1];
    }
  };
  auto loadB = [&](int k0){
    const short* p = brow + (size_t)k0 * 2;
    b0 = *(const bf16x8*)(p);
    b1 = *(const bf16x8*)(p + 8);
    b2 = *(const bf16x8*)(p + 16);
    b3 = *(const bf16x8*)(p + 24);
  };

  loadA(skh);
  loadB(skh);

  const int nkt = Kc / 32;
  for (int kt = 0; kt < nkt; ++kt){
    {
      short hi[16], lo[16];
      #pragma unroll
      for (int j = 0; j < 16; ++j) fsplit_t(va[j], hi[j], lo[j]);
      *(bf16x8*)&sAhi[srow][skh]     = *(bf16x8*)&hi[0];
      *(bf16x8*)&sAhi[srow][skh + 8] = *(bf16x8*)&hi[8];
      *(bf16x8*)&sAlo[srow][skh]     = *(bf16x8*)&lo[0];
      *(bf16x8*)&sAlo[srow][skh + 8] = *(bf16x8*)&lo[8];
      *(bf16x8*)&sBhi[srow][skh]     = b0;
      *(bf16x8*)&sBhi[srow][skh + 8] = b1;
      *(bf16x8*)&sBlo[srow][skh]     = b2;
      *(bf16x8*)&sBlo[srow][skh + 8] = b3;
    }
    __syncthreads();
    if (kt + 1 < nkt){
      loadA((kt + 1) * 32 + skh);
      loadB((kt + 1) * 32 + skh);
    }
    bf16x8 ahi[4], alo[4], bhi[4], blo[4];
    #pragma unroll
    for (int i = 0; i < 4; ++i){
      ahi[i] = *(const bf16x8*)&sAhi[wr + i * 16 + lrow][lkh];
      alo[i] = *(const bf16x8*)&sAlo[wr + i * 16 + lrow][lkh];
    }
    #pragma unroll
    for (int j = 0; j < 4; ++j){
      bhi[j] = *(const bf16x8*)&sBhi[wc + j * 16 + lrow][lkh];
      blo[j] = *(const bf16x8*)&sBlo[wc + j * 16 + lrow][lkh];
    }
    #pragma unroll
    for (int i = 0; i < 4; ++i)
      #pragma unroll
      for (int j = 0; j < 4; ++j){
        acc[i][j] = __builtin_amdgcn_mfma_f32_16x16x32_bf16(ahi[i], bhi[j], acc[i][j], 0, 0, 0);
        acc[i][j] = __builtin_amdgcn_mfma_f32_16x16x32_bf16(ahi[i], blo[j], acc[i][j], 0, 0, 0);
        acc[i][j] = __builtin_amdgcn_mfma_f32_16x16x32_bf16(alo[i], bhi[j], acc[i][j], 0, 0, 0);
      }
    __syncthreads();
  }

  #pragma unroll
  for (int i = 0; i < 4; ++i){
    const int rbase = row0 + wr + i * 16 + (lane >> 4) * 4;
    #pragma unroll
    for (int r = 0; r < 4; ++r){
      const int rg = rbase + r;
      int bt = rg / 192, n = rg - (rg / 192) * 192;
      size_t orow = ((size_t)bt * N_TOK + n + 1) * C_DIM;
      size_t prow = (size_t)(n + 1) * C_DIM;
      #pragma unroll
      for (int j = 0; j < 4; ++j){
        int cg = col0 + wc + j * 16 + (lane & 15);
        C[orow + cg] = acc[i][j][r] + bias[cg] + pos[prow + cg];
      }
    }
  }
}

// ============================ attention (MFMA bf16x2 split; packed output) ============================
__global__ __launch_bounds__(256) void k_attn(const float* __restrict__ qkv, short* __restrict__ opk){
  __shared__ short sQhi[64][72],  sQlo[64][72];
  __shared__ short sKPhi[64][72], sKPlo[64][72];
  __shared__ short sVThi[64][72], sVTlo[64][72];

  const int q0 = blockIdx.x * 64;
  const int bh = blockIdx.y;
  const int bt = bh / N_HEAD, hh = bh - bt * N_HEAD;
  const int tid = threadIdx.x;
  const size_t base = (size_t)bt * N_TOK * QKV_DIM + (size_t)hh * 64;

  const int srow = tid >> 2;
  const int sk   = (tid & 3) * 16;

  { // stage Q
    int q = q0 + srow;
    if (q < N_TOK){
      float v[16];
      const float* src = qkv + base + (size_t)q * QKV_DIM + sk;
      *(float4*)&v[0]  = *(const float4*)(src);
      *(float4*)&v[4]  = *(const float4*)(src + 4);
      *(float4*)&v[8]  = *(const float4*)(src + 8);
      *(float4*)&v[12] = *(const float4*)(src + 12);
      short hi[16], lo[16];
      #pragma unroll
      for (int j = 0; j < 16; ++j) fsplit_t(v[j], hi[j], lo[j]);
      *(bf16x8*)&sQhi[srow][sk]     = *(bf16x8*)&hi[0];
      *(bf16x8*)&sQhi[srow][sk + 8] = *(bf16x8*)&hi[8];
      *(bf16x8*)&sQlo[srow][sk]     = *(bf16x8*)&lo[0];
      *(bf16x8*)&sQlo[srow][sk + 8] = *(bf16x8*)&lo[8];
    } else {
      bf16x8 z = {0,0,0,0,0,0,0,0};
      *(bf16x8*)&sQhi[srow][sk]     = z;
      *(bf16x8*)&sQhi[srow][sk + 8] = z;
      *(bf16x8*)&sQlo[srow][sk]     = z;
      *(bf16x8*)&sQlo[srow][sk + 8] = z;
    }
  }

  const int wv   = tid >> 6;
  const int lane = tid & 63;
  const int lrow = lane & 15;
  const int lkh  = (lane >> 4) * 8;
  const bool wactive = (q0 + wv * 16) < N_TOK;

  f32x4 Oacc[4] = {};
  float mrun[4] = {-1e30f, -1e30f, -1e30f, -1e30f};
  float lrun[4] = {};

  for (int kt = 0; kt < 4; ++kt){
    const int n0 = kt * 64;
    __syncthreads();
    { // stage K + V^T
      int kk = n0 + srow;
      bool valid = kk < N_TOK;
      if (valid){
        float v[16];
        const float* src = qkv + base + 768 + (size_t)kk * QKV_DIM + sk;
        *(float4*)&v[0]  = *(const float4*)(src);
        *(float4*)&v[4]  = *(const float4*)(src + 4);
        *(float4*)&v[8]  = *(const float4*)(src + 8);
        *(float4*)&v[12] = *(const float4*)(src + 12);
        short hi[16], lo[16];
        #pragma unroll
        for (int j = 0; j < 16; ++j) fsplit_t(v[j], hi[j], lo[j]);
        *(bf16x8*)&sKPhi[srow][sk]     = *(bf16x8*)&hi[0];
        *(bf16x8*)&sKPhi[srow][sk + 8] = *(bf16x8*)&hi[8];
        *(bf16x8*)&sKPlo[srow][sk]     = *(bf16x8*)&lo[0];
        *(bf16x8*)&sKPlo[srow][sk + 8] = *(bf16x8*)&lo[8];
        float vv[16];
        const float* srcv = qkv + base + 1536 + (size_t)kk * QKV_DIM + sk;
        *(float4*)&vv[0]  = *(const float4*)(srcv);
        *(float4*)&vv[4]  = *(const float4*)(srcv + 4);
        *(float4*)&vv[8]  = *(const float4*)(srcv + 8);
        *(float4*)&vv[12] = *(const float4*)(srcv + 12);
        #pragma unroll
        for (int j = 0; j < 16; ++j){
          short h2, l2;
          fsplit_t(vv[j], h2, l2);
          sVThi[sk + j][srow] = h2;
          sVTlo[sk + j][srow] = l2;
        }
      } else {
        bf16x8 z = {0,0,0,0,0,0,0,0};
        *(bf16x8*)&sKPhi[srow][sk]     = z;
        *(bf16x8*)&sKPhi[srow][sk + 8] = z;
        *(bf16x8*)&sKPlo[srow][sk]     = z;
        *(bf16x8*)&sKPlo[srow][sk + 8] = z;
        #pragma unroll
        for (int j = 0; j < 16; ++j){
          sVThi[sk + j][srow] = 0;
          sVTlo[sk + j][srow] = 0;
        }
      }
    }
    __syncthreads();

    float p[4][4], fac[4];
    if (wactive){
      f32x4 s[4] = {};
      {
        bf16x8 ahi0 = *(const bf16x8*)&sQhi[wv * 16 + lrow][lkh];
        bf16x8 alo0 = *(const bf16x8*)&sQlo[wv * 16 + lrow][lkh];
        bf16x8 ahi1 = *(const bf16x8*)&sQhi[wv * 16 + lrow][32 + lkh];
        bf16x8 alo1 = *(const bf16x8*)&sQlo[wv * 16 + lrow][32 + lkh];
        #pragma unroll
        for (int j = 0; j < 4; ++j){
          if (n0 + j * 16 >= N_TOK) continue;
          bf16x8 bhi0 = *(const bf16x8*)&sKPhi[j * 16 + lrow][lkh];
          bf16x8 blo0 = *(const bf16x8*)&sKPlo[j * 16 + lrow][lkh];
          bf16x8 bhi1 = *(const bf16x8*)&sKPhi[j * 16 + lrow][32 + lkh];
          bf16x8 blo1 = *(const bf16x8*)&sKPlo[j * 16 + lrow][32 + lkh];
          s[j] = __builtin_amdgcn_mfma_f32_16x16x32_bf16(ahi0, bhi0, s[j], 0, 0, 0);
          s[j] = __builtin_amdgcn_mfma_f32_16x16x32_bf16(ahi0, blo0, s[j], 0, 0, 0);
          s[j] = __builtin_amdgcn_mfma_f32_16x16x32_bf16(alo0, bhi0, s[j], 0, 0, 0);
          s[j] = __builtin_amdgcn_mfma_f32_16x16x32_bf16(ahi1, bhi1, s[j], 0, 0, 0);
          s[j] = __builtin_amdgcn_mfma_f32_16x16x32_bf16(ahi1, blo1, s[j], 0, 0, 0);
          s[j] = __builtin_amdgcn_mfma_f32_16x16x32_bf16(alo1, bhi1, s[j], 0, 0, 0);
        }
      }
      #pragma unroll
      for (int j = 0; j < 4; ++j){
        bool masked = (n0 + j * 16 + lrow) >= N_TOK;
        #pragma unroll
        for (int r = 0; r < 4; ++r){
          s[j][r] *= 0.125f;
          if (masked) s[j][r] = -1e30f;
        }
      }
      #pragma unroll
      for (int r = 0; r < 4; ++r){
        float rm = fmaxf(fmaxf(s[0][r], s[1][r]), fmaxf(s[2][r], s[3][r]));
        rm = fmaxf(rm, __shfl_xor(rm, 1, 64));
        rm = fmaxf(rm, __shfl_xor(rm, 2, 64));
        rm = fmaxf(rm, __shfl_xor(rm, 4, 64));
        rm = fmaxf(rm, __shfl_xor(rm, 8, 64));
        float mn = fmaxf(mrun[r], rm);
        fac[r] = expf(mrun[r] - mn);
        mrun[r] = mn;
        lrun[r] *= fac[r];
        float rs = 0.f;
        #pragma unroll
        for (int j = 0; j < 4; ++j){ p[j][r] = expf(s[j][r] - mn); rs += p[j][r]; }
        rs += __shfl_xor(rs, 1, 64);
        rs += __shfl_xor(rs, 2, 64);
        rs += __shfl_xor(rs, 4, 64);
        rs += __shfl_xor(rs, 8, 64);
        lrun[r] += rs;
        #pragma unroll
        for (int j = 0; j < 4; ++j) Oacc[j][r] *= fac[r];
      }
    }

    __syncthreads();
    if (wactive){
      #pragma unroll
      for (int r = 0; r < 4; ++r){
        const int prow = wv * 16 + (lane >> 4) * 4 + r;
        #pragma unroll
        for (int j = 0; j < 4; ++j){
          short h2, l2;
          fsplit_t(p[j][r], h2, l2);
          sKPhi[prow][j * 16 + lrow] = h2;
          sKPlo[prow][j * 16 + lrow] = l2;
        }
      }
      bf16x8 phi0 = *(const bf16x8*)&sKPhi[wv * 16 + lrow][lkh];
      bf16x8 plo0 = *(const bf16x8*)&sKPlo[wv * 16 + lrow][lkh];
      bf16x8 phi1 = *(const bf16x8*)&sKPhi[wv * 16 + lrow][32 + lkh];
      bf16x8 plo1 = *(const bf16x8*)&sKPlo[wv * 16 + lrow][32 + lkh];
      #pragma unroll
      for (int j = 0; j < 4; ++j){
        bf16x8 vhi0 = *(const bf16x8*)&sVThi[j * 16 + lrow][lkh];
        bf16x8 vlo0 = *(const bf16x8*)&sVTlo[j * 16 + lrow][lkh];
        bf16x8 vhi1 = *(const bf16x8*)&sVThi[j * 16 + lrow][32 + lkh];
        bf16x8 vlo1 = *(const bf16x8*)&sVTlo[j * 16 + lrow][32 + lkh];
        Oacc[j] = __builtin_amdgcn_mfma_f32_16x16x32_bf16(phi0, vhi0, Oacc[j], 0, 0, 0);
        Oacc[j] = __builtin_amdgcn_mfma_f32_16x16x32_bf16(phi0, vlo0, Oacc[j], 0, 0, 0);
        Oacc[j] = __builtin_amdgcn_mfma_f32_16x16x32_bf16(plo0, vhi0, Oacc[j], 0, 0, 0);
        Oacc[j] = __builtin_amdgcn_mfma_f32_16x16x32_bf16(phi1, vhi1, Oacc[j], 0, 0, 0);
        Oacc[j] = __builtin_amdgcn_mfma_f32_16x16x32_bf16(phi1, vlo1, Oacc[j], 0, 0, 0);
        Oacc[j] = __builtin_amdgcn_mfma_f32_16x16x32_bf16(plo1, vhi1, Oacc[j], 0, 0, 0);
      }
    }
  }

  if (wactive){
    #pragma unroll
    for (int r = 0; r < 4; ++r){
      int q = q0 + wv * 16 + (lane >> 4) * 4 + r;
      if (q < N_TOK){
        float inv = 1.0f / lrun[r];
        size_t rowb = ((size_t)bt * N_TOK + q) * C_DIM * 2;
        #pragma unroll
        for (int j = 0; j < 4; ++j){
          float val = Oacc[j][r] * inv;
          short h2, l2;
          fsplit_t(val, h2, l2);
          size_t ix = rowb + (size_t)(hh * 4 + j) * 32 + lrow;
          opk[ix] = h2;
          opk[ix + 16] = l2;
        }
      }
    }
  }
}

// ============================ router v3: 64 tokens/block, LDS-aggregated expert lists ============================
__global__ __launch_bounds__(256) void k_router(
    const float* __restrict__ y, const float* __restrict__ rw, const float* __restrict__ rb,
    const float* __restrict__ rlw, const float* __restrict__ rlb,
    float* __restrict__ topw, int* __restrict__ elist, int* __restrict__ ecnt, int l)
{
  __shared__ float4 sw4[1536];
  __shared__ int lcnt[8];
  __shared__ int lbase[8];
  __shared__ int llist[8][RTOK];
  const int tid = threadIdx.x;
  const float4* rw4 = (const float4*)rw;
  #pragma unroll
  for (int u = 0; u < 6; ++u)
    sw4[tid + u * 256] = rw4[tid + u * 256];
  if (tid < 8) lcnt[tid] = 0;
  __syncthreads();

  const int wid = tid >> 6, lane = tid & 63;
  const int e = lane & 7;

  for (int t16 = 0; t16 < RTOK / 4; ++t16){
    const int tok = blockIdx.x * RTOK + wid * (RTOK / 4) + t16;
    const float4* y4 = (const float4*)(y + (size_t)tok * C_DIM);
    const float4 a0 = y4[lane], a1 = y4[64 + lane], a2 = y4[128 + lane];

    float part[8];
    #pragma unroll
    for (int ee = 0; ee < 8; ++ee){
      const float4 w0 = sw4[ee * 192 + lane];
      const float4 w1 = sw4[ee * 192 + 64 + lane];
      const float4 w2 = sw4[ee * 192 + 128 + lane];
      float s = a0.x * w0.x;
      s = fmaf(a0.y, w0.y, s); s = fmaf(a0.z, w0.z, s); s = fmaf(a0.w, w0.w, s);
      s = fmaf(a1.x, w1.x, s); s = fmaf(a1.y, w1.y, s); s = fmaf(a1.z, w1.z, s); s = fmaf(a1.w, w1.w, s);
      s = fmaf(a2.x, w2.x, s); s = fmaf(a2.y, w2.y, s); s = fmaf(a2.z, w2.z, s); s = fmaf(a2.w, w2.w, s);
      part[ee] = s;
    }
    #pragma unroll
    for (int ee = 0; ee < 8; ++ee)
      #pragma unroll
      for (int off = 32; off; off >>= 1) part[ee] += __shfl_xor(part[ee], off, 64);

    float logit = part[e] + rb[e];
    float ssum = logit;
    ssum += __shfl_xor(ssum, 1, 64); ssum += __shfl_xor(ssum, 2, 64); ssum += __shfl_xor(ssum, 4, 64);
    float mean = ssum * 0.125f;
    float d = logit - mean;
    float vs = d * d;
    vs += __shfl_xor(vs, 1, 64); vs += __shfl_xor(vs, 2, 64); vs += __shfl_xor(vs, 4, 64);
    float ln = d * (1.0f / sqrtf(vs * 0.125f + 1e-5f)) * rlw[e] + rlb[e];
    float mx = ln;
    mx = fmaxf(mx, __shfl_xor(mx, 1, 64)); mx = fmaxf(mx, __shfl_xor(mx, 2, 64)); mx = fmaxf(mx, __shfl_xor(mx, 4, 64));
    float ex = expf(ln - mx);
    float es = ex;
    es += __shfl_xor(es, 1, 64); es += __shfl_xor(es, 2, 64); es += __shfl_xor(es, 4, 64);
    float prob = ex / es;
    int t = tok / 6176;
    int rem = tok - t * 6176;
    int b = rem / N_TOK, n = rem - (rem / N_TOK) * N_TOK;
    uint32_t b0, b1, c0, c1;
    tf2x32(0u, 1234u, 0u, (uint32_t)t, b0, b1);
    tf2x32(b0, b1, 0u, (uint32_t)l, c0, c1);
    uint32_t j = (uint32_t)(b * N_TOK + n) * 8u + (uint32_t)e;
    float r = prob + jax_noise(c0, c1, j);
    float v1 = r; int i1 = e;
    #pragma unroll
    for (int off = 1; off <= 4; off <<= 1){
      float ov = __shfl_xor(v1, off, 64); int oi = __shfl_xor(i1, off, 64);
      if (ov > v1 || (ov == v1 && oi < i1)){ v1 = ov; i1 = oi; }
    }
    float rm2 = (e == i1) ? -3.0e38f : r;
    float v2 = rm2; int i2 = e;
    #pragma unroll
    for (int off = 1; off <= 4; off <<= 1){
      float ov = __shfl_xor(v2, off, 64); int oi = __shfl_xor(i2, off, 64);
      if (ov > v2 || (ov == v2 && oi < i2)){ v2 = ov; i2 = oi; }
    }
    float e2 = expf(v2 - v1);
    float sum = 1.0f + e2;
    if (lane == 0){
      topw[tok * 2 + 0] = 1.0f / sum;
      topw[tok * 2 + 1] = e2 / sum;
      int p = atomicAdd(&lcnt[i1], 1);
      llist[i1][p] = tok * 2;
      int p2 = atomicAdd(&lcnt[i2], 1);
      llist[i2][p2] = tok * 2 + 1;
    }
  }
  __syncthreads();
  if (tid < 8) lbase[tid] = atomicAdd(&ecnt[tid], lcnt[tid]);
  __syncthreads();
  #pragma unroll
  for (int ee = 0; ee < 8; ++ee){
    const int cnt = lcnt[ee];
    const int bse = lbase[ee];
    for (int i = tid; i < cnt; i += 256)
      elist[ee * MAXPER + bse + i] = llist[ee][i];
  }
}

__global__ __launch_bounds__(256) void k_combine(float* __restrict__ h, const float* __restrict__ eout,
                                                 const float* __restrict__ topw){
  const int tok = blockIdx.x;
  const float w0 = topw[tok * 2], w1 = topw[tok * 2 + 1];
  const size_t hb = (size_t)tok * C_DIM;
  const size_t e0 = (size_t)(tok * 2) * C_DIM, e1 = e0 + C_DIM;
  #pragma unroll
  for (int u = 0; u < 3; ++u){
    int c = threadIdx.x + u * 256;
    h[hb + c] += w0 * eout[e0 + c] + w1 * eout[e1 + c];
  }
}

// ============================ host launch ============================
extern "C" void kernel_launch(void* const* d_in, const int* in_sizes, int n_in,
                              void* d_out, int out_size, void* d_ws, size_t ws_size,
                              hipStream_t stream){
  float* out = (float*)d_out;

  static const int kExp[22] = {
    14155776, 14155776, 1769472, 768, 768,
    4608, 4608, 10616832, 13824, 3538944, 4608,
    4608, 4608, 36864, 48, 48, 48,
    28311552, 36864, 768, 768, 148224};
  const size_t W_PATCH = 1769472, W_QKV = 10616832, W_PROJ = 3538944, W_EXP = 28311552;
  const size_t F_BASE = (size_t)ROWS * C_DIM * 2 + (size_t)ROWS * QKV_DIM
                      + (size_t)ROWS * 2 + (size_t)N_EXP * MAXPER + 8;
  const size_t F_YPK  = (size_t)ROWS * C_DIM;                 // packed y (2 shorts/elem = 1 word)
  const size_t F_WSMALL = (size_t)N_EXP * C_DIM * C_DIM;      // largest per-layer tensor
  const size_t F_WFULL  = W_PATCH + W_QKV + W_PROJ + W_EXP;   // all weights packed
  const size_t need_small = F_BASE + F_YPK + F_WSMALL;
  const size_t need_full  = F_BASE + F_YPK + F_WFULL;

  float bad = 0.f;
  if (n_in != 22) bad = 2.0e6f;
  else {
    for (int i = 0; i < 22; ++i)
      if (in_sizes[i] != kExp[i]){ bad = 4.0e6f + i * 1.0e4f; break; }
  }
  if (bad == 0.f && out_size != 49152) bad = 3.0e6f;
  if (bad == 0.f && ws_size < need_small * 4) bad = 1.0e6f;
  if (bad != 0.f){
    k_sentinel<<<dim3(1), 64, 0, stream>>>(out, bad);
    return;
  }
  const bool full = ws_size >= need_full * 4;

  const float* x1       = (const float*)d_in[0];
  const float* x2       = (const float*)d_in[1];
  const float* patch_w  = (const float*)d_in[2];
  const float* patch_b  = (const float*)d_in[3];
  const float* cls_tok  = (const float*)d_in[4];
  const float* ln1_w    = (const float*)d_in[5];
  const float* ln1_b    = (const float*)d_in[6];
  const float* qkv_w    = (const float*)d_in[7];
  const float* qkv_b    = (const float*)d_in[8];
  const float* proj_w   = (const float*)d_in[9];
  const float* proj_b   = (const float*)d_in[10];
  const float* ln2_w    = (const float*)d_in[11];
  const float* ln2_b    = (const float*)d_in[12];
  const float* route_w  = (const float*)d_in[13];
  const float* route_b  = (const float*)d_in[14];
  const float* rln_w    = (const float*)d_in[15];
  const float* rln_b    = (const float*)d_in[16];
  const float* expert_w = (const float*)d_in[17];
  const float* expert_b = (const float*)d_in[18];
  const float* norm_w   = (const float*)d_in[19];
  const float* norm_b   = (const float*)d_in[20];
  const float* pos_emb  = (const float*)d_in[21];

  // workspace: h | y | qkv(eout) | topw | elist | ecnt | ypk | weight-pack region
  float* ws = (float*)d_ws;
  size_t off = 0;
  float* h    = ws + off; off += (size_t)ROWS * C_DIM;
  float* y    = ws + off; off += (size_t)ROWS * C_DIM;
  float* qkv  = ws + off; off += (size_t)ROWS * QKV_DIM;
  float* eout = qkv;
  float* topw = ws + off; off += (size_t)ROWS * 2;
  int*   elist = (int*)(ws + off); off += (size_t)N_EXP * MAXPER;
  int*   ecnt  = (int*)(ws + off); off += 8;
  short* ypk  = (short*)(ws + off); off += F_YPK;
  short* wpk0 = (short*)(ws + off);

  short *pk_patch, *pk_qkv, *pk_proj, *pk_exp;
  if (full){
    pk_patch = wpk0;
    pk_qkv   = pk_patch + W_PATCH * 2;
    pk_proj  = pk_qkv   + W_QKV * 2;
    pk_exp   = pk_proj  + W_PROJ * 2;
    k_wsplit<<<dim3(1024), 256, 0, stream>>>(patch_w,  pk_patch, (int)(W_PATCH / 16));
    k_wsplit<<<dim3(2048), 256, 0, stream>>>(qkv_w,    pk_qkv,   (int)(W_QKV / 16));
    k_wsplit<<<dim3(1024), 256, 0, stream>>>(proj_w,   pk_proj,  (int)(W_PROJ / 16));
    k_wsplit<<<dim3(2048), 256, 0, stream>>>(expert_w, pk_exp,   (int)(W_EXP / 16));
  } else {
    pk_patch = pk_qkv = pk_proj = pk_exp = wpk0;
    k_wsplit<<<dim3(1024), 256, 0, stream>>>(patch_w, wpk0, (int)(W_PATCH / 16));
  }

  // patch embed + cls + pos
  k_cls<<<dim3(B_TOT), 256, 0, stream>>>(h, cls_tok, pos_emb);
  k_mgemm_patch<<<dim3(96, 6), 256, 0, stream>>>(pk_patch, patch_b, h, x1, x2, pos_emb);

  k_layernorm<<<dim3(ROWS), 256, 0, stream>>>(h, nullptr, ypk, ln1_w, ln1_b, nullptr);  // layer-0 ln1
  for (int l = 0; l < 6; ++l){
    const size_t LQ = (size_t)QKV_DIM * C_DIM, LP = (size_t)C_DIM * C_DIM, LE = (size_t)N_EXP * C_DIM * C_DIM;
    const short* wq = full ? pk_qkv + (size_t)l * LQ * 2 : wpk0;
    if (!full) k_wsplit<<<dim3(1024), 256, 0, stream>>>(qkv_w + (size_t)l * LQ, wpk0, (int)(LQ / 16));
    k_pgemm<MODE_PLAIN><<<dim3(97, 18), 256, 0, stream>>>(
        ypk, wq, qkv_b + l * QKV_DIM, qkv, ROWS, QKV_DIM, C_DIM, nullptr, nullptr);
    k_attn<<<dim3(4, B_TOT * N_HEAD), 256, 0, stream>>>(qkv, ypk);   // packed o -> ypk
    const short* wp = full ? pk_proj + (size_t)l * LP * 2 : wpk0;
    if (!full) k_wsplit<<<dim3(512), 256, 0, stream>>>(proj_w + (size_t)l * LP, wpk0, (int)(LP / 16));
    k_pgemm<MODE_RESID><<<dim3(97, 6), 256, 0, stream>>>(
        ypk, wp, proj_b + l * C_DIM, h, ROWS, C_DIM, C_DIM, nullptr, nullptr);
    // ln2: fp32 y (router) + packed y (expert GEMM) + fused ecnt zeroing
    k_layernorm<<<dim3(ROWS), 256, 0, stream>>>(h, y, ypk, ln2_w + l * C_DIM, ln2_b + l * C_DIM, ecnt);
    k_router<<<dim3(ROWS / RTOK), 256, 0, stream>>>(
        y, route_w + (size_t)l * N_EXP * C_DIM, route_b + l * N_EXP,
        rln_w + l * N_EXP, rln_b + l * N_EXP, topw, elist, ecnt, l);
    const short* we = full ? pk_exp + (size_t)l * LE * 2 : wpk0;
    if (!full) k_wsplit<<<dim3(2048), 256, 0, stream>>>(expert_w + (size_t)l * LE, wpk0, (int)(LE / 16));
    k_pgemm<MODE_EXPERT><<<dim3(97, 6, N_EXP), 256, 0, stream>>>(
        ypk, we, expert_b + (size_t)l * N_EXP * C_DIM, eout, ROWS, C_DIM, C_DIM, elist, ecnt);
    if (l < 5){
      k_combine_ln<<<dim3(ROWS), 256, 0, stream>>>(
          h, eout, topw, ypk, ln1_w + (l + 1) * C_DIM, ln1_b + (l + 1) * C_DIM);
    } else {
      k_combine<<<dim3(ROWS), 256, 0, stream>>>(h, eout, topw);
    }
  }
  k_final<<<dim3(B_TOT), 256, 0, stream>>>(h, out, norm_w, norm_b);
}

// Round 21
// 3642.228 us; speedup vs baseline: 1.1411x; 1.1411x over previous
//
#include <hip/hip_runtime.h>
#include <stdint.h>

// ============================ problem constants ============================
#define C_DIM   768
#define N_TOK   193
#define B_TOT   64                    // 2 towers x 32 batch
#define ROWS    (B_TOT * N_TOK)       // 12352
#define QKV_DIM 2304
#define N_HEAD  12
#define N_EXP   8
#define MAXPER  ROWS
#define RTOK    64                    // tokens per router block

enum { MODE_PATCH = 0, MODE_PLAIN = 1, MODE_RESID = 2, MODE_EXPERT = 3 };

typedef __attribute__((ext_vector_type(8))) short bf16x8;
typedef __attribute__((ext_vector_type(4))) float f32x4;

// ============================ threefry-2x32 (bit-exact vs JAX) ============================
__device__ __forceinline__ uint32_t rotl32(uint32_t x, int n){ return (x << n) | (x >> (32 - n)); }

__device__ __forceinline__ void tf2x32(uint32_t k0, uint32_t k1, uint32_t x0, uint32_t x1,
                                       uint32_t &r0, uint32_t &r1){
  uint32_t k2 = k0 ^ k1 ^ 0x1BD11BDAu;
#define TF4(a,b,c,d) x0+=x1; x1=rotl32(x1,a); x1^=x0; x0+=x1; x1=rotl32(x1,b); x1^=x0; \
                     x0+=x1; x1=rotl32(x1,c); x1^=x0; x0+=x1; x1=rotl32(x1,d); x1^=x0;
  x0 += k0; x1 += k1;
  TF4(13,15,26, 6)  x0 += k1; x1 += k2 + 1u;
  TF4(17,29,16,24)  x0 += k2; x1 += k0 + 2u;
  TF4(13,15,26, 6)  x0 += k0; x1 += k1 + 3u;
  TF4(17,29,16,24)  x0 += k1; x1 += k2 + 4u;
  TF4(13,15,26, 6)  x0 += k2; x1 += k0 + 5u;
#undef TF4
  r0 = x0; r1 = x1;
}

__device__ __forceinline__ float jax_erfinv(float x){
  float w = -log1pf(-x * x);
  float p;
  if (w < 5.0f){
    w -= 2.5f;
    p =              2.81022636e-08f;
    p = fmaf(p, w,   3.43273939e-07f);
    p = fmaf(p, w,  -3.5233877e-06f);
    p = fmaf(p, w,  -4.39150654e-06f);
    p = fmaf(p, w,   0.00021858087f);
    p = fmaf(p, w,  -0.00125372503f);
    p = fmaf(p, w,  -0.00417768164f);
    p = fmaf(p, w,   0.246640727f);
    p = fmaf(p, w,   1.50140941f);
  } else {
    w = sqrtf(w) - 3.0f;
    p =             -0.000200214257f;
    p = fmaf(p, w,   0.000100950558f);
    p = fmaf(p, w,   0.00134934322f);
    p = fmaf(p, w,  -0.00367342844f);
    p = fmaf(p, w,   0.00573950773f);
    p = fmaf(p, w,  -0.0076224613f);
    p = fmaf(p, w,   0.00943887047f);
    p = fmaf(p, w,   1.00167406f);
    p = fmaf(p, w,   2.83297682f);
  }
  return p * x;
}

// PARTITIONABLE threefry random_bits (JAX >= 0.4.36 default) [verified round 5]
__device__ __forceinline__ float jax_noise(uint32_t c0, uint32_t c1, uint32_t j){
  uint32_t o0, o1;
  tf2x32(c0, c1, 0u, j, o0, o1);
  uint32_t bits = o0 ^ o1;
  float f = __uint_as_float(0x3f800000u | (bits >> 9)) - 1.0f;   // [0,1)
  const float lo = -0.99999994f;                                  // nextafter(-1,0)
  float u = fmaxf(lo, f * 2.0f + lo);
  return 1.41421356237f * jax_erfinv(u) * 0.125f;                 // sqrt(2)*erfinv(u)/E
}

// ============================ bf16 split helpers ============================
__device__ __forceinline__ unsigned short f2bf(float x){
  union { float f; uint32_t u; } v; v.f = x;
  uint32_t u = v.u;
  uint32_t r = (u + 0x7FFFu + ((u >> 16) & 1u)) >> 16;   // RNE
  return (unsigned short)r;
}
__device__ __forceinline__ float bf2f(unsigned short h){
  union { uint32_t u; float f; } v; v.u = ((uint32_t)h) << 16;
  return v.f;
}
// truncation split: hi = trunc_bf16(x) (x - hi exact); lo = RNE_bf16(x - hi). [validated R15/R16]
__device__ __forceinline__ void fsplit_t(float x, short &hi, short &lo){
  union { float f; uint32_t u; } v; v.f = x;
  uint32_t hb = v.u & 0xFFFF0000u;
  hi = (short)(hb >> 16);
  union { uint32_t u; float f; } hv; hv.u = hb;
  lo = (short)f2bf(x - hv.f);
}

// ============================ small kernels ============================
__global__ __launch_bounds__(64) void k_sentinel(float* __restrict__ out, float v){
  if (threadIdx.x == 0) out[0] = v;
}

__global__ __launch_bounds__(256) void k_cls(float* __restrict__ h, const float* __restrict__ cls,
                                             const float* __restrict__ pos){
  const int bt = blockIdx.x;
  #pragma unroll
  for (int u = 0; u < 3; ++u){
    int c = threadIdx.x + u * 256;
    h[(size_t)bt * N_TOK * C_DIM + c] = cls[c] + pos[c];
  }
}

__device__ __forceinline__ float blk_sum(float v, float* sb){
  #pragma unroll
  for (int off = 32; off > 0; off >>= 1) v += __shfl_down(v, off, 64);
  const int lane = threadIdx.x & 63, w = threadIdx.x >> 6;
  if (lane == 0) sb[w] = v;
  __syncthreads();
  if (threadIdx.x == 0) sb[4] = sb[0] + sb[1] + sb[2] + sb[3];
  __syncthreads();
  float r = sb[4];
  __syncthreads();
  return r;
}

// layernorm; block 0 optionally zeroes ecnt (fused k_zero8 — stream-ordered before router)
__global__ __launch_bounds__(256) void k_layernorm(const float* __restrict__ x, float* __restrict__ y,
                                                   const float* __restrict__ w, const float* __restrict__ b,
                                                   int* __restrict__ ecnt){
  __shared__ float sb[8];
  if (ecnt && blockIdx.x == 0 && threadIdx.x < N_EXP) ecnt[threadIdx.x] = 0;
  const float* xr = x + (size_t)blockIdx.x * C_DIM;
  float v0 = xr[threadIdx.x], v1 = xr[threadIdx.x + 256], v2 = xr[threadIdx.x + 512];
  float mean = blk_sum(v0 + v1 + v2, sb) * (1.0f / 768.0f);
  float d0 = v0 - mean, d1 = v1 - mean, d2 = v2 - mean;
  float var = blk_sum(d0 * d0 + d1 * d1 + d2 * d2, sb) * (1.0f / 768.0f);
  float inv = 1.0f / sqrtf(var + 1e-5f);
  float* yr = y + (size_t)blockIdx.x * C_DIM;
  yr[threadIdx.x]       = d0 * inv * w[threadIdx.x]       + b[threadIdx.x];
  yr[threadIdx.x + 256] = d1 * inv * w[threadIdx.x + 256] + b[threadIdx.x + 256];
  yr[threadIdx.x + 512] = d2 * inv * w[threadIdx.x + 512] + b[threadIdx.x + 512];
}

// combine (h += w0*e0 + w1*e1) fused with the NEXT layer's ln1 (row-local ops)
__global__ __launch_bounds__(256) void k_combine_ln(
    float* __restrict__ h, const float* __restrict__ eout, const float* __restrict__ topw,
    float* __restrict__ y, const float* __restrict__ w, const float* __restrict__ b)
{
  __shared__ float sb[8];
  const int tok = blockIdx.x;
  const float w0 = topw[tok * 2], w1 = topw[tok * 2 + 1];
  const size_t hb = (size_t)tok * C_DIM;
  const size_t e0 = (size_t)(tok * 2) * C_DIM, e1 = e0 + C_DIM;
  const int t = threadIdx.x;
  float v0 = h[hb + t]       + (w0 * eout[e0 + t]       + w1 * eout[e1 + t]);
  float v1 = h[hb + t + 256] + (w0 * eout[e0 + t + 256] + w1 * eout[e1 + t + 256]);
  float v2 = h[hb + t + 512] + (w0 * eout[e0 + t + 512] + w1 * eout[e1 + t + 512]);
  h[hb + t]       = v0;
  h[hb + t + 256] = v1;
  h[hb + t + 512] = v2;
  float mean = blk_sum(v0 + v1 + v2, sb) * (1.0f / 768.0f);
  float d0 = v0 - mean, d1 = v1 - mean, d2 = v2 - mean;
  float var = blk_sum(d0 * d0 + d1 * d1 + d2 * d2, sb) * (1.0f / 768.0f);
  float inv = 1.0f / sqrtf(var + 1e-5f);
  y[hb + t]       = d0 * inv * w[t]       + b[t];
  y[hb + t + 256] = d1 * inv * w[t + 256] + b[t + 256];
  y[hb + t + 512] = d2 * inv * w[t + 512] + b[t + 512];
}

__global__ __launch_bounds__(256) void k_final(const float* __restrict__ h, float* __restrict__ out,
                                               const float* __restrict__ w, const float* __restrict__ b){
  __shared__ float sb[8];
  const int bt = blockIdx.x;
  const float* xr = h + (size_t)bt * N_TOK * C_DIM;
  float v0 = xr[threadIdx.x], v1 = xr[threadIdx.x + 256], v2 = xr[threadIdx.x + 512];
  float mean = blk_sum(v0 + v1 + v2, sb) * (1.0f / 768.0f);
  float d0 = v0 - mean, d1 = v1 - mean, d2 = v2 - mean;
  float var = blk_sum(d0 * d0 + d1 * d1 + d2 * d2, sb) * (1.0f / 768.0f);
  float inv = 1.0f / sqrtf(var + 1e-5f);
  float* orow = out + (size_t)(bt & 31) * 1536 + (size_t)(bt >> 5) * C_DIM;
  orow[threadIdx.x]       = d0 * inv * w[threadIdx.x]       + b[threadIdx.x];
  orow[threadIdx.x + 256] = d1 * inv * w[threadIdx.x + 256] + b[threadIdx.x + 256];
  orow[threadIdx.x + 512] = d2 * inv * w[threadIdx.x + 512] + b[threadIdx.x + 512];
}

// ============================ MFMA GEMM (bf16x2 trunc-split, reg-prefetch; R16 structure) ============================
template<int MODE>
__global__ __launch_bounds__(256) void k_mgemm(
    const float* __restrict__ A, const float* __restrict__ W,
    const float* __restrict__ bias, float* __restrict__ C,
    int M, int Nc, int Kc,
    const float* __restrict__ xa, const float* __restrict__ xb,
    const float* __restrict__ pos,
    const int* __restrict__ elist, const int* __restrict__ ecnt)
{
  __shared__ short sAhi[128][40];
  __shared__ short sAlo[128][40];
  __shared__ short sBhi[128][40];
  __shared__ short sBlo[128][40];

  const int tid = threadIdx.x;

  int e = 0;
  int Mloc = M;
  const float* Wp = W;
  const float* bp = bias;
  if constexpr (MODE == MODE_EXPERT){
    e = blockIdx.z;
    Mloc = ecnt[e];
    Wp = W + (size_t)e * C_DIM * C_DIM;
    bp = bias + e * C_DIM;
  }
  const int row0 = blockIdx.x * 128;
  const int col0 = blockIdx.y * 128;
  if (row0 >= Mloc) return;

  const int srow = tid >> 1;
  const int skh  = (tid & 1) * 16;

  const float* arow = A;
  bool avalid = false;
  const float* psrc = nullptr;
  if constexpr (MODE == MODE_PLAIN || MODE == MODE_RESID){
    int r = row0 + srow;
    avalid = r < Mloc;
    arow = A + (size_t)(avalid ? r : 0) * Kc;
  } else if constexpr (MODE == MODE_EXPERT){
    int r = row0 + srow;
    avalid = r < Mloc;
    if (avalid) arow = A + (size_t)(elist[e * MAXPER + r] >> 1) * C_DIM;
  } else {
    int r = row0 + srow;
    int bt = r / 192;
    int n  = r - bt * 192;
    const float* xp = (bt < 32) ? xa : xb;
    psrc = xp + (size_t)(bt & 31) * 3 * 384 * 384 + n * 2;
    avalid = true;
  }
  const float* brow = Wp + (size_t)(col0 + srow) * Kc;

  const int wv = tid >> 6;
  const int wr = (wv >> 1) * 64;
  const int wc = (wv & 1) * 64;
  const int lane = tid & 63;
  const int lrow = lane & 15;
  const int lkh  = (lane >> 4) * 8;

  f32x4 acc[4][4] = {};

  float va[16], vb[16];
  auto loadA = [&](int k0){
    if constexpr (MODE == MODE_PATCH){
      int c   = k0 / 768;
      int rem = k0 - c * 768;
      const float* pc = psrc + ((size_t)c * 384 + (rem >> 1)) * 384;
      #pragma unroll
      for (int m = 0; m < 8; ++m){
        va[m * 2 + 0] = pc[(size_t)m * 384 + 0];
        va[m * 2 + 1] = pc[(size_t)m * 384 + 1];
      }
    } else {
      if (avalid){
        *(float4*)&va[0]  = *(const float4*)(arow + k0);
        *(float4*)&va[4]  = *(const float4*)(arow + k0 + 4);
        *(float4*)&va[8]  = *(const float4*)(arow + k0 + 8);
        *(float4*)&va[12] = *(const float4*)(arow + k0 + 12);
      } else {
        #pragma unroll
        for (int j = 0; j < 16; ++j) va[j] = 0.f;
      }
    }
  };
  auto loadB = [&](int k0){
    *(float4*)&vb[0]  = *(const float4*)(brow + k0);
    *(float4*)&vb[4]  = *(const float4*)(brow + k0 + 4);
    *(float4*)&vb[8]  = *(const float4*)(brow + k0 + 8);
    *(float4*)&vb[12] = *(const float4*)(brow + k0 + 12);
  };

  loadA(skh);
  loadB(skh);

  const int nkt = Kc / 32;
  for (int kt = 0; kt < nkt; ++kt){
    {
      short hi[16], lo[16];
      #pragma unroll
      for (int j = 0; j < 16; ++j) fsplit_t(va[j], hi[j], lo[j]);
      *(bf16x8*)&sAhi[srow][skh]     = *(bf16x8*)&hi[0];
      *(bf16x8*)&sAhi[srow][skh + 8] = *(bf16x8*)&hi[8];
      *(bf16x8*)&sAlo[srow][skh]     = *(bf16x8*)&lo[0];
      *(bf16x8*)&sAlo[srow][skh + 8] = *(bf16x8*)&lo[8];
      #pragma unroll
      for (int j = 0; j < 16; ++j) fsplit_t(vb[j], hi[j], lo[j]);
      *(bf16x8*)&sBhi[srow][skh]     = *(bf16x8*)&hi[0];
      *(bf16x8*)&sBhi[srow][skh + 8] = *(bf16x8*)&hi[8];
      *(bf16x8*)&sBlo[srow][skh]     = *(bf16x8*)&lo[0];
      *(bf16x8*)&sBlo[srow][skh + 8] = *(bf16x8*)&lo[8];
    }
    __syncthreads();
    if (kt + 1 < nkt){
      loadA((kt + 1) * 32 + skh);
      loadB((kt + 1) * 32 + skh);
    }
    bf16x8 ahi[4], alo[4], bhi[4], blo[4];
    #pragma unroll
    for (int i = 0; i < 4; ++i){
      ahi[i] = *(const bf16x8*)&sAhi[wr + i * 16 + lrow][lkh];
      alo[i] = *(const bf16x8*)&sAlo[wr + i * 16 + lrow][lkh];
    }
    #pragma unroll
    for (int j = 0; j < 4; ++j){
      bhi[j] = *(const bf16x8*)&sBhi[wc + j * 16 + lrow][lkh];
      blo[j] = *(const bf16x8*)&sBlo[wc + j * 16 + lrow][lkh];
    }
    #pragma unroll
    for (int i = 0; i < 4; ++i)
      #pragma unroll
      for (int j = 0; j < 4; ++j){
        acc[i][j] = __builtin_amdgcn_mfma_f32_16x16x32_bf16(ahi[i], bhi[j], acc[i][j], 0, 0, 0);
        acc[i][j] = __builtin_amdgcn_mfma_f32_16x16x32_bf16(ahi[i], blo[j], acc[i][j], 0, 0, 0);
        acc[i][j] = __builtin_amdgcn_mfma_f32_16x16x32_bf16(alo[i], bhi[j], acc[i][j], 0, 0, 0);
      }
    __syncthreads();
  }

  #pragma unroll
  for (int i = 0; i < 4; ++i){
    const int rbase = row0 + wr + i * 16 + (lane >> 4) * 4;
    #pragma unroll
    for (int r = 0; r < 4; ++r){
      const int rg = rbase + r;
      if (rg >= Mloc) continue;
      if constexpr (MODE == MODE_PATCH){
        int bt = rg / 192, n = rg - (rg / 192) * 192;
        size_t orow = ((size_t)bt * N_TOK + n + 1) * C_DIM;
        size_t prow = (size_t)(n + 1) * C_DIM;
        #pragma unroll
        for (int j = 0; j < 4; ++j){
          int cg = col0 + wc + j * 16 + (lane & 15);
          C[orow + cg] = acc[i][j][r] + bp[cg] + pos[prow + cg];
        }
      } else if constexpr (MODE == MODE_PLAIN){
        size_t orow = (size_t)rg * Nc;
        #pragma unroll
        for (int j = 0; j < 4; ++j){
          int cg = col0 + wc + j * 16 + (lane & 15);
          C[orow + cg] = acc[i][j][r] + bp[cg];
        }
      } else if constexpr (MODE == MODE_RESID){
        size_t orow = (size_t)rg * Nc;
        #pragma unroll
        for (int j = 0; j < 4; ++j){
          int cg = col0 + wc + j * 16 + (lane & 15);
          C[orow + cg] += acc[i][j][r] + bp[cg];
        }
      } else {
        int ts = elist[e * MAXPER + rg];
        size_t orow = (size_t)ts * C_DIM;
        #pragma unroll
        for (int j = 0; j < 4; ++j){
          int cg = col0 + wc + j * 16 + (lane & 15);
          C[orow + cg] = acc[i][j][r] + bp[cg];
        }
      }
    }
  }
}

// ============================ attention (flash-style, MFMA bf16x2 split; padding-waste trimmed) ============================
__global__ __launch_bounds__(256) void k_attn(const float* __restrict__ qkv, float* __restrict__ o_out){
  __shared__ short sQhi[64][72],  sQlo[64][72];
  __shared__ short sKPhi[64][72], sKPlo[64][72];
  __shared__ short sVThi[64][72], sVTlo[64][72];

  const int q0 = blockIdx.x * 64;
  const int bh = blockIdx.y;
  const int bt = bh / N_HEAD, hh = bh - bt * N_HEAD;
  const int tid = threadIdx.x;
  const size_t base = (size_t)bt * N_TOK * QKV_DIM + (size_t)hh * 64;

  const int srow = tid >> 2;
  const int sk   = (tid & 3) * 16;

  { // stage Q
    int q = q0 + srow;
    if (q < N_TOK){
      float v[16];
      const float* src = qkv + base + (size_t)q * QKV_DIM + sk;
      *(float4*)&v[0]  = *(const float4*)(src);
      *(float4*)&v[4]  = *(const float4*)(src + 4);
      *(float4*)&v[8]  = *(const float4*)(src + 8);
      *(float4*)&v[12] = *(const float4*)(src + 12);
      short hi[16], lo[16];
      #pragma unroll
      for (int j = 0; j < 16; ++j){
        unsigned short hb = f2bf(v[j]);
        hi[j] = (short)hb;
        lo[j] = (short)f2bf(v[j] - bf2f(hb));
      }
      *(bf16x8*)&sQhi[srow][sk]     = *(bf16x8*)&hi[0];
      *(bf16x8*)&sQhi[srow][sk + 8] = *(bf16x8*)&hi[8];
      *(bf16x8*)&sQlo[srow][sk]     = *(bf16x8*)&lo[0];
      *(bf16x8*)&sQlo[srow][sk + 8] = *(bf16x8*)&lo[8];
    } else {
      bf16x8 z = {0,0,0,0,0,0,0,0};
      *(bf16x8*)&sQhi[srow][sk]     = z;
      *(bf16x8*)&sQhi[srow][sk + 8] = z;
      *(bf16x8*)&sQlo[srow][sk]     = z;
      *(bf16x8*)&sQlo[srow][sk + 8] = z;
    }
  }

  const int wv   = tid >> 6;
  const int lane = tid & 63;
  const int lrow = lane & 15;
  const int lkh  = (lane >> 4) * 8;
  const bool wactive = (q0 + wv * 16) < N_TOK;   // wave owns at least one valid q-row

  f32x4 Oacc[4] = {};
  float mrun[4] = {-1e30f, -1e30f, -1e30f, -1e30f};
  float lrun[4] = {};

  for (int kt = 0; kt < 4; ++kt){
    const int n0 = kt * 64;
    __syncthreads();
    { // stage K + V^T (zero fast-path for invalid rows: skips conversion)
      int kk = n0 + srow;
      bool valid = kk < N_TOK;
      if (valid){
        float v[16];
        const float* src = qkv + base + 768 + (size_t)kk * QKV_DIM + sk;
        *(float4*)&v[0]  = *(const float4*)(src);
        *(float4*)&v[4]  = *(const float4*)(src + 4);
        *(float4*)&v[8]  = *(const float4*)(src + 8);
        *(float4*)&v[12] = *(const float4*)(src + 12);
        short hi[16], lo[16];
        #pragma unroll
        for (int j = 0; j < 16; ++j){
          unsigned short hb = f2bf(v[j]);
          hi[j] = (short)hb;
          lo[j] = (short)f2bf(v[j] - bf2f(hb));
        }
        *(bf16x8*)&sKPhi[srow][sk]     = *(bf16x8*)&hi[0];
        *(bf16x8*)&sKPhi[srow][sk + 8] = *(bf16x8*)&hi[8];
        *(bf16x8*)&sKPlo[srow][sk]     = *(bf16x8*)&lo[0];
        *(bf16x8*)&sKPlo[srow][sk + 8] = *(bf16x8*)&lo[8];
        float vv[16];
        const float* srcv = qkv + base + 1536 + (size_t)kk * QKV_DIM + sk;
        *(float4*)&vv[0]  = *(const float4*)(srcv);
        *(float4*)&vv[4]  = *(const float4*)(srcv + 4);
        *(float4*)&vv[8]  = *(const float4*)(srcv + 8);
        *(float4*)&vv[12] = *(const float4*)(srcv + 12);
        #pragma unroll
        for (int j = 0; j < 16; ++j){
          unsigned short hb = f2bf(vv[j]);
          sVThi[sk + j][srow] = (short)hb;
          sVTlo[sk + j][srow] = (short)f2bf(vv[j] - bf2f(hb));
        }
      } else {
        bf16x8 z = {0,0,0,0,0,0,0,0};
        *(bf16x8*)&sKPhi[srow][sk]     = z;
        *(bf16x8*)&sKPhi[srow][sk + 8] = z;
        *(bf16x8*)&sKPlo[srow][sk]     = z;
        *(bf16x8*)&sKPlo[srow][sk + 8] = z;
        #pragma unroll
        for (int j = 0; j < 16; ++j){
          sVThi[sk + j][srow] = 0;
          sVTlo[sk + j][srow] = 0;
        }
      }
    }
    __syncthreads();

    float p[4][4], fac[4];
    if (wactive){
      f32x4 s[4] = {};
      {
        bf16x8 ahi0 = *(const bf16x8*)&sQhi[wv * 16 + lrow][lkh];
        bf16x8 alo0 = *(const bf16x8*)&sQlo[wv * 16 + lrow][lkh];
        bf16x8 ahi1 = *(const bf16x8*)&sQhi[wv * 16 + lrow][32 + lkh];
        bf16x8 alo1 = *(const bf16x8*)&sQlo[wv * 16 + lrow][32 + lkh];
        #pragma unroll
        for (int j = 0; j < 4; ++j){
          if (n0 + j * 16 >= N_TOK) continue;     // fully-masked col-subtile: skip MFMAs
          bf16x8 bhi0 = *(const bf16x8*)&sKPhi[j * 16 + lrow][lkh];
          bf16x8 blo0 = *(const bf16x8*)&sKPlo[j * 16 + lrow][lkh];
          bf16x8 bhi1 = *(const bf16x8*)&sKPhi[j * 16 + lrow][32 + lkh];
          bf16x8 blo1 = *(const bf16x8*)&sKPlo[j * 16 + lrow][32 + lkh];
          s[j] = __builtin_amdgcn_mfma_f32_16x16x32_bf16(ahi0, bhi0, s[j], 0, 0, 0);
          s[j] = __builtin_amdgcn_mfma_f32_16x16x32_bf16(ahi0, blo0, s[j], 0, 0, 0);
          s[j] = __builtin_amdgcn_mfma_f32_16x16x32_bf16(alo0, bhi0, s[j], 0, 0, 0);
          s[j] = __builtin_amdgcn_mfma_f32_16x16x32_bf16(ahi1, bhi1, s[j], 0, 0, 0);
          s[j] = __builtin_amdgcn_mfma_f32_16x16x32_bf16(ahi1, blo1, s[j], 0, 0, 0);
          s[j] = __builtin_amdgcn_mfma_f32_16x16x32_bf16(alo1, bhi1, s[j], 0, 0, 0);
        }
      }
      #pragma unroll
      for (int j = 0; j < 4; ++j){
        bool masked = (n0 + j * 16 + lrow) >= N_TOK;
        #pragma unroll
        for (int r = 0; r < 4; ++r){
          s[j][r] *= 0.125f;
          if (masked) s[j][r] = -1e30f;
        }
      }

      #pragma unroll
      for (int r = 0; r < 4; ++r){
        float rm = fmaxf(fmaxf(s[0][r], s[1][r]), fmaxf(s[2][r], s[3][r]));
        rm = fmaxf(rm, __shfl_xor(rm, 1, 64));
        rm = fmaxf(rm, __shfl_xor(rm, 2, 64));
        rm = fmaxf(rm, __shfl_xor(rm, 4, 64));
        rm = fmaxf(rm, __shfl_xor(rm, 8, 64));
        float mn = fmaxf(mrun[r], rm);
        fac[r] = expf(mrun[r] - mn);
        mrun[r] = mn;
        lrun[r] *= fac[r];
        float rs = 0.f;
        #pragma unroll
        for (int j = 0; j < 4; ++j){ p[j][r] = expf(s[j][r] - mn); rs += p[j][r]; }
        rs += __shfl_xor(rs, 1, 64);
        rs += __shfl_xor(rs, 2, 64);
        rs += __shfl_xor(rs, 4, 64);
        rs += __shfl_xor(rs, 8, 64);
        lrun[r] += rs;
        #pragma unroll
        for (int j = 0; j < 4; ++j) Oacc[j][r] *= fac[r];
      }
    }

    __syncthreads();
    if (wactive){
      #pragma unroll
      for (int r = 0; r < 4; ++r){
        const int prow = wv * 16 + (lane >> 4) * 4 + r;
        #pragma unroll
        for (int j = 0; j < 4; ++j){
          unsigned short hb = f2bf(p[j][r]);
          sKPhi[prow][j * 16 + lrow] = (short)hb;
          sKPlo[prow][j * 16 + lrow] = (short)f2bf(p[j][r] - bf2f(hb));
        }
      }

      bf16x8 phi0 = *(const bf16x8*)&sKPhi[wv * 16 + lrow][lkh];
      bf16x8 plo0 = *(const bf16x8*)&sKPlo[wv * 16 + lrow][lkh];
      bf16x8 phi1 = *(const bf16x8*)&sKPhi[wv * 16 + lrow][32 + lkh];
      bf16x8 plo1 = *(const bf16x8*)&sKPlo[wv * 16 + lrow][32 + lkh];
      #pragma unroll
      for (int j = 0; j < 4; ++j){
        bf16x8 vhi0 = *(const bf16x8*)&sVThi[j * 16 + lrow][lkh];
        bf16x8 vlo0 = *(const bf16x8*)&sVTlo[j * 16 + lrow][lkh];
        bf16x8 vhi1 = *(const bf16x8*)&sVThi[j * 16 + lrow][32 + lkh];
        bf16x8 vlo1 = *(const bf16x8*)&sVTlo[j * 16 + lrow][32 + lkh];
        Oacc[j] = __builtin_amdgcn_mfma_f32_16x16x32_bf16(phi0, vhi0, Oacc[j], 0, 0, 0);
        Oacc[j] = __builtin_amdgcn_mfma_f32_16x16x32_bf16(phi0, vlo0, Oacc[j], 0, 0, 0);
        Oacc[j] = __builtin_amdgcn_mfma_f32_16x16x32_bf16(plo0, vhi0, Oacc[j], 0, 0, 0);
        Oacc[j] = __builtin_amdgcn_mfma_f32_16x16x32_bf16(phi1, vhi1, Oacc[j], 0, 0, 0);
        Oacc[j] = __builtin_amdgcn_mfma_f32_16x16x32_bf16(phi1, vlo1, Oacc[j], 0, 0, 0);
        Oacc[j] = __builtin_amdgcn_mfma_f32_16x16x32_bf16(plo1, vhi1, Oacc[j], 0, 0, 0);
      }
    }
  }

  if (wactive){
    #pragma unroll
    for (int r = 0; r < 4; ++r){
      int q = q0 + wv * 16 + (lane >> 4) * 4 + r;
      if (q < N_TOK){
        float inv = 1.0f / lrun[r];
        #pragma unroll
        for (int j = 0; j < 4; ++j)
          o_out[((size_t)bt * N_TOK + q) * C_DIM + hh * 64 + j * 16 + lrow] = Oacc[j][r] * inv;
      }
    }
  }
}

// ============================ router v3: 64 tokens/block, LDS-aggregated expert lists ============================
__global__ __launch_bounds__(256) void k_router(
    const float* __restrict__ y, const float* __restrict__ rw, const float* __restrict__ rb,
    const float* __restrict__ rlw, const float* __restrict__ rlb,
    float* __restrict__ topw, int* __restrict__ elist, int* __restrict__ ecnt, int l)
{
  __shared__ float4 sw4[1536];
  __shared__ int lcnt[8];
  __shared__ int lbase[8];
  __shared__ int llist[8][RTOK];
  const int tid = threadIdx.x;
  const float4* rw4 = (const float4*)rw;
  #pragma unroll
  for (int u = 0; u < 6; ++u)
    sw4[tid + u * 256] = rw4[tid + u * 256];
  if (tid < 8) lcnt[tid] = 0;
  __syncthreads();

  const int wid = tid >> 6, lane = tid & 63;
  const int e = lane & 7;

  for (int t16 = 0; t16 < RTOK / 4; ++t16){
    const int tok = blockIdx.x * RTOK + wid * (RTOK / 4) + t16;
    const float4* y4 = (const float4*)(y + (size_t)tok * C_DIM);
    const float4 a0 = y4[lane], a1 = y4[64 + lane], a2 = y4[128 + lane];

    float part[8];
    #pragma unroll
    for (int ee = 0; ee < 8; ++ee){
      const float4 w0 = sw4[ee * 192 + lane];
      const float4 w1 = sw4[ee * 192 + 64 + lane];
      const float4 w2 = sw4[ee * 192 + 128 + lane];
      float s = a0.x * w0.x;
      s = fmaf(a0.y, w0.y, s); s = fmaf(a0.z, w0.z, s); s = fmaf(a0.w, w0.w, s);
      s = fmaf(a1.x, w1.x, s); s = fmaf(a1.y, w1.y, s); s = fmaf(a1.z, w1.z, s); s = fmaf(a1.w, w1.w, s);
      s = fmaf(a2.x, w2.x, s); s = fmaf(a2.y, w2.y, s); s = fmaf(a2.z, w2.z, s); s = fmaf(a2.w, w2.w, s);
      part[ee] = s;
    }
    #pragma unroll
    for (int ee = 0; ee < 8; ++ee)
      #pragma unroll
      for (int off = 32; off; off >>= 1) part[ee] += __shfl_xor(part[ee], off, 64);

    float logit = part[e] + rb[e];
    float ssum = logit;
    ssum += __shfl_xor(ssum, 1, 64); ssum += __shfl_xor(ssum, 2, 64); ssum += __shfl_xor(ssum, 4, 64);
    float mean = ssum * 0.125f;
    float d = logit - mean;
    float vs = d * d;
    vs += __shfl_xor(vs, 1, 64); vs += __shfl_xor(vs, 2, 64); vs += __shfl_xor(vs, 4, 64);
    float ln = d * (1.0f / sqrtf(vs * 0.125f + 1e-5f)) * rlw[e] + rlb[e];
    float mx = ln;
    mx = fmaxf(mx, __shfl_xor(mx, 1, 64)); mx = fmaxf(mx, __shfl_xor(mx, 2, 64)); mx = fmaxf(mx, __shfl_xor(mx, 4, 64));
    float ex = expf(ln - mx);
    float es = ex;
    es += __shfl_xor(es, 1, 64); es += __shfl_xor(es, 2, 64); es += __shfl_xor(es, 4, 64);
    float prob = ex / es;
    int t = tok / 6176;
    int rem = tok - t * 6176;
    int b = rem / N_TOK, n = rem - (rem / N_TOK) * N_TOK;
    uint32_t b0, b1, c0, c1;
    tf2x32(0u, 1234u, 0u, (uint32_t)t, b0, b1);
    tf2x32(b0, b1, 0u, (uint32_t)l, c0, c1);
    uint32_t j = (uint32_t)(b * N_TOK + n) * 8u + (uint32_t)e;
    float r = prob + jax_noise(c0, c1, j);
    float v1 = r; int i1 = e;
    #pragma unroll
    for (int off = 1; off <= 4; off <<= 1){
      float ov = __shfl_xor(v1, off, 64); int oi = __shfl_xor(i1, off, 64);
      if (ov > v1 || (ov == v1 && oi < i1)){ v1 = ov; i1 = oi; }
    }
    float rm2 = (e == i1) ? -3.0e38f : r;
    float v2 = rm2; int i2 = e;
    #pragma unroll
    for (int off = 1; off <= 4; off <<= 1){
      float ov = __shfl_xor(v2, off, 64); int oi = __shfl_xor(i2, off, 64);
      if (ov > v2 || (ov == v2 && oi < i2)){ v2 = ov; i2 = oi; }
    }
    float e2 = expf(v2 - v1);
    float sum = 1.0f + e2;
    if (lane == 0){
      topw[tok * 2 + 0] = 1.0f / sum;
      topw[tok * 2 + 1] = e2 / sum;
      int p = atomicAdd(&lcnt[i1], 1);
      llist[i1][p] = tok * 2;
      int p2 = atomicAdd(&lcnt[i2], 1);
      llist[i2][p2] = tok * 2 + 1;
    }
  }
  __syncthreads();
  if (tid < 8) lbase[tid] = atomicAdd(&ecnt[tid], lcnt[tid]);
  __syncthreads();
  #pragma unroll
  for (int ee = 0; ee < 8; ++ee){
    const int cnt = lcnt[ee];
    const int bse = lbase[ee];
    for (int i = tid; i < cnt; i += 256)
      elist[ee * MAXPER + bse + i] = llist[ee][i];
  }
}

__global__ __launch_bounds__(256) void k_combine(float* __restrict__ h, const float* __restrict__ eout,
                                                 const float* __restrict__ topw){
  const int tok = blockIdx.x;
  const float w0 = topw[tok * 2], w1 = topw[tok * 2 + 1];
  const size_t hb = (size_t)tok * C_DIM;
  const size_t e0 = (size_t)(tok * 2) * C_DIM, e1 = e0 + C_DIM;
  #pragma unroll
  for (int u = 0; u < 3; ++u){
    int c = threadIdx.x + u * 256;
    h[hb + c] += w0 * eout[e0 + c] + w1 * eout[e1 + c];
  }
}

// ============================ host launch ============================
extern "C" void kernel_launch(void* const* d_in, const int* in_sizes, int n_in,
                              void* d_out, int out_size, void* d_ws, size_t ws_size,
                              hipStream_t stream){
  float* out = (float*)d_out;

  static const int kExp[22] = {
    14155776, 14155776, 1769472, 768, 768,
    4608, 4608, 10616832, 13824, 3538944, 4608,
    4608, 4608, 36864, 48, 48, 48,
    28311552, 36864, 768, 768, 148224};
  const size_t need_f = (size_t)ROWS * C_DIM * 2 + (size_t)ROWS * QKV_DIM
                      + (size_t)ROWS * 2 + (size_t)N_EXP * MAXPER + 8;
  float bad = 0.f;
  if (n_in != 22) bad = 2.0e6f;
  else {
    for (int i = 0; i < 22; ++i)
      if (in_sizes[i] != kExp[i]){ bad = 4.0e6f + i * 1.0e4f; break; }
  }
  if (bad == 0.f && out_size != 49152) bad = 3.0e6f;
  if (bad == 0.f && ws_size < need_f * 4) bad = 1.0e6f;
  if (bad != 0.f){
    k_sentinel<<<dim3(1), 64, 0, stream>>>(out, bad);
    return;
  }

  const float* x1       = (const float*)d_in[0];
  const float* x2       = (const float*)d_in[1];
  const float* patch_w  = (const float*)d_in[2];
  const float* patch_b  = (const float*)d_in[3];
  const float* cls_tok  = (const float*)d_in[4];
  const float* ln1_w    = (const float*)d_in[5];
  const float* ln1_b    = (const float*)d_in[6];
  const float* qkv_w    = (const float*)d_in[7];
  const float* qkv_b    = (const float*)d_in[8];
  const float* proj_w   = (const float*)d_in[9];
  const float* proj_b   = (const float*)d_in[10];
  const float* ln2_w    = (const float*)d_in[11];
  const float* ln2_b    = (const float*)d_in[12];
  const float* route_w  = (const float*)d_in[13];
  const float* route_b  = (const float*)d_in[14];
  const float* rln_w    = (const float*)d_in[15];
  const float* rln_b    = (const float*)d_in[16];
  const float* expert_w = (const float*)d_in[17];
  const float* expert_b = (const float*)d_in[18];
  const float* norm_w   = (const float*)d_in[19];
  const float* norm_b   = (const float*)d_in[20];
  const float* pos_emb  = (const float*)d_in[21];

  // workspace layout (fp32): h | y | qkv (eout aliases qkv) | topw | elist | ecnt
  float* ws = (float*)d_ws;
  size_t off = 0;
  float* h    = ws + off; off += (size_t)ROWS * C_DIM;
  float* y    = ws + off; off += (size_t)ROWS * C_DIM;
  float* qkv  = ws + off; off += (size_t)ROWS * QKV_DIM;
  float* eout = qkv;
  float* topw = ws + off; off += (size_t)ROWS * 2;
  int*   elist = (int*)(ws + off); off += (size_t)N_EXP * MAXPER;
  int*   ecnt  = (int*)(ws + off); off += 8;

  // patch embed + cls + pos
  k_cls<<<dim3(B_TOT), 256, 0, stream>>>(h, cls_tok, pos_emb);
  k_mgemm<MODE_PATCH><<<dim3(96, 6), 256, 0, stream>>>(
      nullptr, patch_w, patch_b, h, 12288, C_DIM, 2304, x1, x2, pos_emb, nullptr, nullptr);

  k_layernorm<<<dim3(ROWS), 256, 0, stream>>>(h, y, ln1_w, ln1_b, nullptr);   // layer-0 ln1
  for (int l = 0; l < 6; ++l){
    k_mgemm<MODE_PLAIN><<<dim3(97, 18), 256, 0, stream>>>(
        y, qkv_w + (size_t)l * QKV_DIM * C_DIM, qkv_b + l * QKV_DIM, qkv,
        ROWS, QKV_DIM, C_DIM, nullptr, nullptr, nullptr, nullptr, nullptr);
    k_attn<<<dim3(4, B_TOT * N_HEAD), 256, 0, stream>>>(qkv, y);   // o -> y
    k_mgemm<MODE_RESID><<<dim3(97, 6), 256, 0, stream>>>(
        y, proj_w + (size_t)l * C_DIM * C_DIM, proj_b + l * C_DIM, h,
        ROWS, C_DIM, C_DIM, nullptr, nullptr, nullptr, nullptr, nullptr);
    // ln2 + fused ecnt zeroing (stream-ordered before router)
    k_layernorm<<<dim3(ROWS), 256, 0, stream>>>(h, y, ln2_w + l * C_DIM, ln2_b + l * C_DIM, ecnt);
    k_router<<<dim3(ROWS / RTOK), 256, 0, stream>>>(
        y, route_w + (size_t)l * N_EXP * C_DIM, route_b + l * N_EXP,
        rln_w + l * N_EXP, rln_b + l * N_EXP, topw, elist, ecnt, l);
    k_mgemm<MODE_EXPERT><<<dim3(97, 6, N_EXP), 256, 0, stream>>>(
        y, expert_w + (size_t)l * N_EXP * C_DIM * C_DIM, expert_b + (size_t)l * N_EXP * C_DIM, eout,
        ROWS, C_DIM, C_DIM, nullptr, nullptr, nullptr, elist, ecnt);
    if (l < 5){
      k_combine_ln<<<dim3(ROWS), 256, 0, stream>>>(
          h, eout, topw, y, ln1_w + (l + 1) * C_DIM, ln1_b + (l + 1) * C_DIM);
    } else {
      k_combine<<<dim3(ROWS), 256, 0, stream>>>(h, eout, topw);
    }
  }
  k_final<<<dim3(B_TOT), 256, 0, stream>>>(h, out, norm_w, norm_b);
}